// Round 12
// baseline (334.288 us; speedup 1.0000x reference)
//
#include <hip/hip_runtime.h>
#include <hip/hip_bf16.h>
#include <cfloat>

#define DIM 690
#define NCHUNK 22
#define N_CLS 53
#define YLD 64            // y row stride in shorts (128 B rows)
#define BM 16             // rows per slab
#define LDS_LD 696        // LDS row stride in shorts: 1392 B, 16B-aligned, uniform-conflict b128
#define GRID_SCORE 768    // 3 blocks/CU x 256 CU (persistent)
#define NSLAB 16384       // 262144 / BM

typedef short bf16x8 __attribute__((ext_vector_type(8)));
typedef float f32x4  __attribute__((ext_vector_type(4)));

static __device__ __forceinline__ unsigned int f2bf(float f) {
    __hip_bfloat16 h = __float2bfloat16(f);
    return (unsigned int)*reinterpret_cast<unsigned short*>(&h);
}
static __device__ __forceinline__ float bflo(unsigned int v) {
    union { unsigned int u; float f; } c; c.u = v << 16; return c.f;
}
static __device__ __forceinline__ float bfhi(unsigned int v) {
    union { unsigned int u; float f; } c; c.u = v & 0xFFFF0000u; return c.f;
}

// ---------------------------------------------------------------------------
// P0: pack BOTH weight blocks in MFMA fragment order:
//   wbp[((kk*4+kg)*64 + c)*8 + j] = bf16(rel_w[c][k])
//   awp[  same layout           ] = bf16(att_w[c][k] * rel_w[c][k])  (fp32 mul)
// with k = kk*32 + kg*8 + j; zero-padded for c>=53 or k>=690.
// ---------------------------------------------------------------------------
__global__ __launch_bounds__(256) void prep_kernel(
    const float* __restrict__ rel_w, const float* __restrict__ att_w,
    unsigned short* __restrict__ wbp, unsigned short* __restrict__ awp)
{
    int idx = blockIdx.x * blockDim.x + threadIdx.x;
    const int NW = NCHUNK * 4 * 512;   // 45056
    if (idx >= 2 * NW) return;
    int which = idx >= NW;
    int j = which ? idx - NW : idx;
    int kkg = j >> 9;                  // kk*4+kg
    int rem = j & 511;
    int c = rem >> 3, jj = rem & 7;
    int k = (kkg >> 2) * 32 + (kkg & 3) * 8 + jj;
    float v = 0.f;
    if (c < N_CLS && k < DIM) {
        float rv = rel_w[c * DIM + k];
        v = which ? att_w[c * DIM + k] * rv : rv;
    }
    (which ? awp : wbp)[j] = (unsigned short)f2bf(v);
}

// ---------------------------------------------------------------------------
// K1: fused score GEMM + MFMA attention logit — R8 skeleton, wave-pair split.
// 256 threads: waves 0-1 compute y cols (wv&1)*32..+31 vs wbp; waves 2-3
// compute the same cols of the aw-score vs awp, into awt LDS (parity dbuf).
// Each wave: ONE B-array, TWO imm-offset loads per chunk (+0, +128 shorts),
// 2 MFMAs, 1 ds_read_b128. logit[r] = awt[r][query[r]] extracted for slab
// t-1 after the slab barrier (sealed). Persistent blocks, BM=16 slabs,
// double-buffered xs, ONE __syncthreads per slab, T14 load-early/write-late
// (16 threads per row, 11 float4 loads).
// A/B frag: k = 8*(lane>>4)+j, A row / B col = lane&15.
// D frag: col = lane&15, row = (lane>>4)*4 + reg.
// ---------------------------------------------------------------------------
__global__ __launch_bounds__(256, 3) void score_kernel(
    const float* __restrict__ x,
    const unsigned short* __restrict__ wbp,
    const unsigned short* __restrict__ awp,
    const int* __restrict__ query,
    unsigned short* __restrict__ y,
    float* __restrict__ logit)
{
    __shared__ unsigned short xs[2][BM * LDS_LD + 8];
    __shared__ float awt[2][BM][64];

    const int t = threadIdx.x;
    const int lane = t & 63;
    const int wv = t >> 6;
    const int r = lane & 15, kg = lane >> 4;
    const int srow = t >> 4, sub = t & 15;   // stage: 16 threads per row

    // zero per-row pads (cols 690..695) and the 8-short tile tail, both bufs:
    // kk=21 fragment tails must read finite values (paired B is exact 0).
    if (t < 104) {
        int b = t >= 52; int j = b ? t - 52 : t;
        unsigned int off;  // u32 index within buffer
        if (j < 48) { int row = j / 3, c = j % 3; off = (unsigned)(row * LDS_LD + 690) / 2 + c; }
        else        { off = (unsigned)(BM * LDS_LD) / 2 + (j - 48); }
        reinterpret_cast<unsigned int*>(xs[b])[off] = 0u;
    }

    float4 sreg[11];

    auto load_slab = [&](int s) {
        const float* xrow = x + ((size_t)s * BM + srow) * DIM;
        #pragma unroll
        for (int i = 0; i < 10; ++i)
            sreg[i] = *reinterpret_cast<const float4*>(xrow + i * 64 + sub * 4);
        if (sub < 12)
            sreg[10] = *reinterpret_cast<const float4*>(xrow + 640 + sub * 4);
        else if (sub == 12) {
            float2 v = *reinterpret_cast<const float2*>(xrow + 688);
            sreg[10] = make_float4(v.x, v.y, 0.f, 0.f);
        }
    };
    auto write_slab = [&](int b) {
        unsigned short* base = xs[b] + srow * LDS_LD;
        #pragma unroll
        for (int i = 0; i < 10; ++i) {
            uint2 p = make_uint2(f2bf(sreg[i].x) | (f2bf(sreg[i].y) << 16),
                                 f2bf(sreg[i].z) | (f2bf(sreg[i].w) << 16));
            *reinterpret_cast<uint2*>(base + i * 64 + sub * 4) = p;
        }
        if (sub < 12) {
            uint2 p = make_uint2(f2bf(sreg[10].x) | (f2bf(sreg[10].y) << 16),
                                 f2bf(sreg[10].z) | (f2bf(sreg[10].w) << 16));
            *reinterpret_cast<uint2*>(base + 640 + sub * 4) = p;
        } else if (sub == 12) {
            *reinterpret_cast<unsigned int*>(base + 688) =
                f2bf(sreg[10].x) | (f2bf(sreg[10].y) << 16);
        }
    };

    int slab = blockIdx.x;
    load_slab(slab);
    write_slab(0);
    __syncthreads();

    const int cb2 = (wv & 1) * 32;     // wave-pair column base
    const unsigned short* fbase =
        (wv < 2 ? wbp : awp) + (size_t)((kg * 64 + cb2 + r) * 8);

    int buf = 0, it = 0, prev = -1;
    while (true) {
        const int next = slab + GRID_SCORE;
        const bool has_next = next < NSLAB;

        if (has_next) load_slab(next);     // issue-early (T14)

        // ---- compute current slab: 22 chunks x 2 MFMAs per wave ----
        {
            const int rowBase = slab * BM;
            const unsigned short* xbase = xs[buf] + r * LDS_LD;
            f32x4 acc0 = {0.f, 0.f, 0.f, 0.f};
            f32x4 acc1 = {0.f, 0.f, 0.f, 0.f};
            #pragma unroll
            for (int kk = 0; kk < NCHUNK; ++kk) {
                bf16x8 af = *reinterpret_cast<const bf16x8*>(xbase + kk * 32 + kg * 8);
                const unsigned short* bp = fbase + (size_t)kk * 2048;
                bf16x8 b0 = *reinterpret_cast<const bf16x8*>(bp);
                bf16x8 b1 = *reinterpret_cast<const bf16x8*>(bp + 128); // +16 cols
                acc0 = __builtin_amdgcn_mfma_f32_16x16x32_bf16(af, b0, acc0, 0, 0, 0);
                acc1 = __builtin_amdgcn_mfma_f32_16x16x32_bf16(af, b1, acc1, 0, 0, 0);
            }
            if (wv < 2) {
                #pragma unroll
                for (int reg = 0; reg < 4; ++reg) {
                    size_t base = (size_t)(rowBase + kg * 4 + reg) * YLD;
                    y[base + cb2 + r]      = (unsigned short)f2bf(acc0[reg]);
                    y[base + cb2 + 16 + r] = (unsigned short)f2bf(acc1[reg]);
                }
            } else {
                #pragma unroll
                for (int reg = 0; reg < 4; ++reg) {
                    awt[it & 1][kg * 4 + reg][cb2 + r]      = acc0[reg];
                    awt[it & 1][kg * 4 + reg][cb2 + 16 + r] = acc1[reg];
                }
            }
        }

        // extract previous slab's logit from its sealed aw D-tile
        if (prev >= 0 && t < 16)
            logit[prev * BM + t] = awt[(it - 1) & 1][t][query[prev * BM + t]];

        if (has_next) write_slab(buf ^ 1); // write-late
        __syncthreads();                   // single barrier per slab

        if (!has_next) break;
        prev = slab; slab = next; buf ^= 1; ++it;
    }
    // final slab's logit (sealed by the loop's last barrier)
    if (t < 16)
        logit[slab * BM + t] = awt[it & 1][t][query[slab * BM + t]];
}

// ---------------------------------------------------------------------------
// K2: one block (4 waves) per bag. Wave lanes: cq=lane&15 -> cols 4cq..4cq+3
// (uint2 = 4 bf16), rq=lane>>4 -> row offset. Per instruction: 4 rows x
// 128 B contiguous. Col-indexed LDS reduce across waves.
// ---------------------------------------------------------------------------
__global__ __launch_bounds__(256) void bag_kernel(
    const unsigned short* __restrict__ y,
    const float* __restrict__ logit,
    const float* __restrict__ bias,
    const int* __restrict__ scope,
    float* __restrict__ out)
{
    const int bag = blockIdx.x;
    const int t = threadIdx.x, lane = t & 63, wv = t >> 6;
    const int s = scope[bag], e = scope[bag + 1];

    __shared__ float red[4][64];

    float m = -FLT_MAX;
    for (int i = s + lane; i < e; i += 64) m = fmaxf(m, logit[i]);
    #pragma unroll
    for (int off = 32; off > 0; off >>= 1) m = fmaxf(m, __shfl_xor(m, off));

    float sum = 0.f;
    for (int i = s + lane; i < e; i += 64) sum += __expf(logit[i] - m);
    #pragma unroll
    for (int off = 32; off > 0; off >>= 1) sum += __shfl_xor(sum, off);
    const float inv = 1.f / sum;

    const int cq = lane & 15;          // col quad: cols 4cq..4cq+3
    const int rq = lane >> 4;          // row offset 0..3
    const uint2* yu = reinterpret_cast<const uint2*>(y);

    float a0 = 0.f, a1 = 0.f, a2 = 0.f, a3 = 0.f;
    for (int base = s + wv * 4; base < e; base += 16) {
        int row = base + rq;
        if (row < e) {
            float w = __expf(logit[row] - m) * inv;
            uint2 v = yu[(size_t)row * (YLD / 4) + cq];
            a0 += w * bflo(v.x);
            a1 += w * bfhi(v.x);
            a2 += w * bflo(v.y);
            a3 += w * bfhi(v.y);
        }
    }
    a0 += __shfl_xor(a0, 16); a0 += __shfl_xor(a0, 32);
    a1 += __shfl_xor(a1, 16); a1 += __shfl_xor(a1, 32);
    a2 += __shfl_xor(a2, 16); a2 += __shfl_xor(a2, 32);
    a3 += __shfl_xor(a3, 16); a3 += __shfl_xor(a3, 32);
    if (lane < 16) {
        red[wv][4 * lane + 0] = a0;
        red[wv][4 * lane + 1] = a1;
        red[wv][4 * lane + 2] = a2;
        red[wv][4 * lane + 3] = a3;
    }
    __syncthreads();
    if (t < N_CLS)
        out[(size_t)bag * N_CLS + t] =
            red[0][t] + red[1][t] + red[2][t] + red[3][t] + bias[t];
}

// ---------------------------------------------------------------------------
extern "C" void kernel_launch(void* const* d_in, const int* in_sizes, int n_in,
                              void* d_out, int out_size, void* d_ws, size_t ws_size,
                              hipStream_t stream)
{
    const float* x     = (const float*)d_in[0];
    const float* rel_w = (const float*)d_in[1];
    const float* att_w = (const float*)d_in[2];
    const float* bias  = (const float*)d_in[3];
    const int*   query = (const int*)d_in[4];
    const int*   scope = (const int*)d_in[5];
    float*       out   = (float*)d_out;

    const int n_sent = in_sizes[0] / DIM;      // 262144
    const int n_bags = in_sizes[5] - 1;        // 8192

    // workspace layout
    const int NW = NCHUNK * 4 * 512;                           // 45056 shorts
    unsigned short* wbp   = (unsigned short*)d_ws;             // NW
    unsigned short* awp   = wbp + NW;                          // NW
    float*          logit = (float*)(awp + NW);                // n_sent
    unsigned short* y     = (unsigned short*)(logit + n_sent); // n_sent*YLD

    prep_kernel<<<(2 * NW + 255) / 256, 256, 0, stream>>>(rel_w, att_w, wbp, awp);

    score_kernel<<<GRID_SCORE, 256, 0, stream>>>(x, wbp, awp, query, y, logit);

    bag_kernel<<<n_bags, 256, 0, stream>>>(y, logit, bias, scope, out);
}

// Round 13
// 196.009 us; speedup vs baseline: 1.7055x; 1.7055x over previous
//
#include <hip/hip_runtime.h>
#include <hip/hip_bf16.h>
#include <cfloat>

#define DIM 690
#define NCHUNK 22
#define N_CLS 53
#define YLD 64            // y row stride in shorts (128 B rows)
#define BM 16             // rows per slab
#define LDS_LD 696        // LDS row stride in shorts: 1392 B, 16B-aligned, uniform-conflict b128
#define AWLD 704          // aw row stride in shorts (zero-padded)
#define NSLAB 16384       // 262144 / BM

typedef short bf16x8 __attribute__((ext_vector_type(8)));
typedef float f32x4  __attribute__((ext_vector_type(4)));

static __device__ __forceinline__ unsigned int f2bf(float f) {
    __hip_bfloat16 h = __float2bfloat16(f);
    return (unsigned int)*reinterpret_cast<unsigned short*>(&h);
}
static __device__ __forceinline__ float bflo(unsigned int v) {
    union { unsigned int u; float f; } c; c.u = v << 16; return c.f;
}
static __device__ __forceinline__ float bfhi(unsigned int v) {
    union { unsigned int u; float f; } c; c.u = v & 0xFFFF0000u; return c.f;
}

// ---------------------------------------------------------------------------
// P0: pack
//  wbp — fragment-ordered B: wbp[((kk*4+kg)*64 + c)*8 + j] = bf16(rel_w[c][k]),
//        k = kk*32 + kg*8 + j, zero-padded (c>=53 or k>=690)
//  awb — row-major bf16(att*rel) [53][704] (fp32 product), zero-padded
// ---------------------------------------------------------------------------
__global__ __launch_bounds__(256) void prep_kernel(
    const float* __restrict__ rel_w, const float* __restrict__ att_w,
    unsigned short* __restrict__ wbp, unsigned short* __restrict__ awb)
{
    int idx = blockIdx.x * blockDim.x + threadIdx.x;
    const int NW = NCHUNK * 4 * 512;   // 45056
    const int NA = N_CLS * AWLD;       // 37312
    if (idx < NW) {
        int kkg = idx >> 9;            // kk*4+kg
        int rem = idx & 511;
        int c = rem >> 3, j = rem & 7;
        int k = (kkg >> 2) * 32 + (kkg & 3) * 8 + j;
        float v = (c < N_CLS && k < DIM) ? rel_w[c * DIM + k] : 0.f;
        wbp[idx] = (unsigned short)f2bf(v);
    } else if (idx < NW + NA) {
        int i2 = idx - NW;
        int c = i2 / AWLD, k = i2 - c * AWLD;
        float v = (k < DIM) ? att_w[c * DIM + k] * rel_w[c * DIM + k] : 0.f;
        awb[i2] = (unsigned short)f2bf(v);
    }
}

// ---------------------------------------------------------------------------
// K1: fused score GEMM + staged-register attention logit — ONE-SHOT blocks.
// grid = NSLAB; block b owns slab b. Single-buffered LDS (22.3 KB) +
// launch_bounds(256,4) -> 4 blocks/CU, 16 waves/CU; pipelining comes from
// the HW scheduler interleaving independent blocks at different phases.
// Per block: load 16x690 fp32 (11 float4/thread, 16 thr/row) -> logit dot
// (fp32 sreg vs bf16 aw row, L2-hot, coalesced) -> bf16 convert + ds_write
// -> barrier -> 22 chunks {ds_read_b128 A, b128 wbp frag, MFMA} -> y store.
// A/B frag: k = 8*(lane>>4)+j, A row / B col = lane&15.
// D frag: col = lane&15, row = (lane>>4)*4 + reg.
// ---------------------------------------------------------------------------
__global__ __launch_bounds__(256, 4) void score_kernel(
    const float* __restrict__ x,
    const unsigned short* __restrict__ wbp,
    const unsigned short* __restrict__ awb,
    const int* __restrict__ query,
    unsigned short* __restrict__ y,
    float* __restrict__ logit)
{
    __shared__ unsigned short xs[BM * LDS_LD + 8];

    const int t = threadIdx.x;
    const int lane = t & 63;
    const int wv = t >> 6;
    const int r = lane & 15, kg = lane >> 4;
    const int srow = t >> 4, sub = t & 15;   // stage: 16 threads per row
    const int slab = blockIdx.x;

    // zero per-row pads (cols 690..695) and the 8-short tile tail:
    // kk=21 fragment tails must read finite values (paired B is exact 0).
    if (t < 52) {
        unsigned int off;  // u32 index within buffer
        if (t < 48) { int row = t / 3, c = t % 3; off = (unsigned)(row * LDS_LD + 690) / 2 + c; }
        else        { off = (unsigned)(BM * LDS_LD) / 2 + (t - 48); }
        reinterpret_cast<unsigned int*>(xs)[off] = 0u;
    }

    float4 sreg[11];

    // ---- stage loads (issue-early) ----
    {
        const float* xrow = x + ((size_t)slab * BM + srow) * DIM;
        #pragma unroll
        for (int i = 0; i < 10; ++i)
            sreg[i] = *reinterpret_cast<const float4*>(xrow + i * 64 + sub * 4);
        if (sub < 12)
            sreg[10] = *reinterpret_cast<const float4*>(xrow + 640 + sub * 4);
        else if (sub == 12) {
            float2 v = *reinterpret_cast<const float2*>(xrow + 688);
            sreg[10] = make_float4(v.x, v.y, 0.f, 0.f);
        }
    }

    // ---- logit dot: fp32 sreg vs bf16 aw row (row-shared -> coalesced) ----
    {
        const int q = query[slab * BM + srow];
        const unsigned short* awrow = awb + (size_t)q * AWLD;
        float lg = 0.f;
        #pragma unroll
        for (int i = 0; i < 10; ++i) {
            uint2 v = *reinterpret_cast<const uint2*>(awrow + i * 64 + sub * 4);
            lg += sreg[i].x * bflo(v.x) + sreg[i].y * bfhi(v.x)
                + sreg[i].z * bflo(v.y) + sreg[i].w * bfhi(v.y);
        }
        if (sub < 12) {
            uint2 v = *reinterpret_cast<const uint2*>(awrow + 640 + sub * 4);
            lg += sreg[10].x * bflo(v.x) + sreg[10].y * bfhi(v.x)
                + sreg[10].z * bflo(v.y) + sreg[10].w * bfhi(v.y);
        } else if (sub == 12) {
            unsigned int v = *reinterpret_cast<const unsigned int*>(awrow + 688);
            lg += sreg[10].x * bflo(v) + sreg[10].y * bfhi(v);
        }
        lg += __shfl_xor(lg, 1);
        lg += __shfl_xor(lg, 2);
        lg += __shfl_xor(lg, 4);
        lg += __shfl_xor(lg, 8);
        if (sub == 0) logit[slab * BM + srow] = lg;
    }

    // ---- bf16 convert + LDS write ----
    {
        unsigned short* base = xs + srow * LDS_LD;
        #pragma unroll
        for (int i = 0; i < 10; ++i) {
            uint2 p = make_uint2(f2bf(sreg[i].x) | (f2bf(sreg[i].y) << 16),
                                 f2bf(sreg[i].z) | (f2bf(sreg[i].w) << 16));
            *reinterpret_cast<uint2*>(base + i * 64 + sub * 4) = p;
        }
        if (sub < 12) {
            uint2 p = make_uint2(f2bf(sreg[10].x) | (f2bf(sreg[10].y) << 16),
                                 f2bf(sreg[10].z) | (f2bf(sreg[10].w) << 16));
            *reinterpret_cast<uint2*>(base + 640 + sub * 4) = p;
        } else if (sub == 12) {
            *reinterpret_cast<unsigned int*>(base + 688) =
                f2bf(sreg[10].x) | (f2bf(sreg[10].y) << 16);
        }
    }
    __syncthreads();

    // ---- compute: 22 chunks, pure GEMM from LDS ----
    {
        const unsigned short* xbase = xs + r * LDS_LD;
        const unsigned short* fbase = wbp + (size_t)((kg * 64 + wv * 16 + r) * 8);
        f32x4 acc = {0.f, 0.f, 0.f, 0.f};
        #pragma unroll
        for (int kk = 0; kk < NCHUNK; ++kk) {
            bf16x8 af = *reinterpret_cast<const bf16x8*>(xbase + kk * 32 + kg * 8);
            bf16x8 bw = *reinterpret_cast<const bf16x8*>(fbase + (size_t)kk * 2048);
            acc = __builtin_amdgcn_mfma_f32_16x16x32_bf16(af, bw, acc, 0, 0, 0);
        }
        const int rowBase = slab * BM;
        #pragma unroll
        for (int reg = 0; reg < 4; ++reg)
            y[(size_t)(rowBase + kg * 4 + reg) * YLD + wv * 16 + r] =
                (unsigned short)f2bf(acc[reg]);
    }
}

// ---------------------------------------------------------------------------
// K2: one block (4 waves) per bag. Wave lanes: cq=lane&15 -> cols 4cq..4cq+3
// (uint2 = 4 bf16), rq=lane>>4 -> row offset. Per instruction: 4 rows x
// 128 B contiguous. Col-indexed LDS reduce across waves.
// ---------------------------------------------------------------------------
__global__ __launch_bounds__(256) void bag_kernel(
    const unsigned short* __restrict__ y,
    const float* __restrict__ logit,
    const float* __restrict__ bias,
    const int* __restrict__ scope,
    float* __restrict__ out)
{
    const int bag = blockIdx.x;
    const int t = threadIdx.x, lane = t & 63, wv = t >> 6;
    const int s = scope[bag], e = scope[bag + 1];

    __shared__ float red[4][64];

    float m = -FLT_MAX;
    for (int i = s + lane; i < e; i += 64) m = fmaxf(m, logit[i]);
    #pragma unroll
    for (int off = 32; off > 0; off >>= 1) m = fmaxf(m, __shfl_xor(m, off));

    float sum = 0.f;
    for (int i = s + lane; i < e; i += 64) sum += __expf(logit[i] - m);
    #pragma unroll
    for (int off = 32; off > 0; off >>= 1) sum += __shfl_xor(sum, off);
    const float inv = 1.f / sum;

    const int cq = lane & 15;          // col quad: cols 4cq..4cq+3
    const int rq = lane >> 4;          // row offset 0..3
    const uint2* yu = reinterpret_cast<const uint2*>(y);

    float a0 = 0.f, a1 = 0.f, a2 = 0.f, a3 = 0.f;
    for (int base = s + wv * 4; base < e; base += 16) {
        int row = base + rq;
        if (row < e) {
            float w = __expf(logit[row] - m) * inv;
            uint2 v = yu[(size_t)row * (YLD / 4) + cq];
            a0 += w * bflo(v.x);
            a1 += w * bfhi(v.x);
            a2 += w * bflo(v.y);
            a3 += w * bfhi(v.y);
        }
    }
    a0 += __shfl_xor(a0, 16); a0 += __shfl_xor(a0, 32);
    a1 += __shfl_xor(a1, 16); a1 += __shfl_xor(a1, 32);
    a2 += __shfl_xor(a2, 16); a2 += __shfl_xor(a2, 32);
    a3 += __shfl_xor(a3, 16); a3 += __shfl_xor(a3, 32);
    if (lane < 16) {
        red[wv][4 * lane + 0] = a0;
        red[wv][4 * lane + 1] = a1;
        red[wv][4 * lane + 2] = a2;
        red[wv][4 * lane + 3] = a3;
    }
    __syncthreads();
    if (t < N_CLS)
        out[(size_t)bag * N_CLS + t] =
            red[0][t] + red[1][t] + red[2][t] + red[3][t] + bias[t];
}

// ---------------------------------------------------------------------------
extern "C" void kernel_launch(void* const* d_in, const int* in_sizes, int n_in,
                              void* d_out, int out_size, void* d_ws, size_t ws_size,
                              hipStream_t stream)
{
    const float* x     = (const float*)d_in[0];
    const float* rel_w = (const float*)d_in[1];
    const float* att_w = (const float*)d_in[2];
    const float* bias  = (const float*)d_in[3];
    const int*   query = (const int*)d_in[4];
    const int*   scope = (const int*)d_in[5];
    float*       out   = (float*)d_out;

    const int n_sent = in_sizes[0] / DIM;      // 262144
    const int n_bags = in_sizes[5] - 1;        // 8192

    // workspace layout
    const int NW = NCHUNK * 4 * 512;                           // 45056 shorts
    const int NA = N_CLS * AWLD;                               // 37312 shorts
    unsigned short* wbp   = (unsigned short*)d_ws;             // NW
    unsigned short* awb   = wbp + NW;                          // NA
    float*          logit = (float*)(awb + NA);                // n_sent
    unsigned short* y     = (unsigned short*)(logit + n_sent); // n_sent*YLD

    prep_kernel<<<(NW + NA + 255) / 256, 256, 0, stream>>>(rel_w, att_w, wbp, awb);

    score_kernel<<<NSLAB, 256, 0, stream>>>(x, wbp, awb, query, y, logit);

    bag_kernel<<<n_bags, 256, 0, stream>>>(y, logit, bias, scope, out);
}

// Round 14
// 195.462 us; speedup vs baseline: 1.7102x; 1.0028x over previous
//
#include <hip/hip_runtime.h>
#include <hip/hip_bf16.h>
#include <cfloat>

#define DIM 690
#define NCHUNK 22
#define N_CLS 53
#define YLD 64            // y row stride in shorts (128 B rows)
#define BM 16             // rows per slab
#define LDS_LD 696        // LDS row stride in shorts: 1392 B, 16B-aligned, uniform-conflict b128
#define AWLD 704          // aw row stride in shorts (zero-padded)
#define NSLAB 16384       // 262144 / BM

typedef short bf16x8 __attribute__((ext_vector_type(8)));
typedef float f32x4  __attribute__((ext_vector_type(4)));

static __device__ __forceinline__ unsigned int f2bf(float f) {
    __hip_bfloat16 h = __float2bfloat16(f);
    return (unsigned int)*reinterpret_cast<unsigned short*>(&h);
}
static __device__ __forceinline__ float bflo(unsigned int v) {
    union { unsigned int u; float f; } c; c.u = v << 16; return c.f;
}
static __device__ __forceinline__ float bfhi(unsigned int v) {
    union { unsigned int u; float f; } c; c.u = v & 0xFFFF0000u; return c.f;
}

// ---------------------------------------------------------------------------
// P0: pack
//  wbp — fragment-ordered B: wbp[((kk*4+kg)*64 + c)*8 + j] = bf16(rel_w[c][k]),
//        k = kk*32 + kg*8 + j, zero-padded (c>=53 or k>=690)
//  awb — row-major bf16(att*rel) [53][704] (fp32 product), zero-padded
// ---------------------------------------------------------------------------
__global__ __launch_bounds__(256) void prep_kernel(
    const float* __restrict__ rel_w, const float* __restrict__ att_w,
    unsigned short* __restrict__ wbp, unsigned short* __restrict__ awb)
{
    int idx = blockIdx.x * blockDim.x + threadIdx.x;
    const int NW = NCHUNK * 4 * 512;   // 45056
    const int NA = N_CLS * AWLD;       // 37312
    if (idx < NW) {
        int kkg = idx >> 9;            // kk*4+kg
        int rem = idx & 511;
        int c = rem >> 3, j = rem & 7;
        int k = (kkg >> 2) * 32 + (kkg & 3) * 8 + j;
        float v = (c < N_CLS && k < DIM) ? rel_w[c * DIM + k] : 0.f;
        wbp[idx] = (unsigned short)f2bf(v);
    } else if (idx < NW + NA) {
        int i2 = idx - NW;
        int c = i2 / AWLD, k = i2 - c * AWLD;
        float v = (k < DIM) ? att_w[c * DIM + k] * rel_w[c * DIM + k] : 0.f;
        awb[i2] = (unsigned short)f2bf(v);
    }
}

// ---------------------------------------------------------------------------
// K1: fused score GEMM + staged-register attention logit — ONE-SHOT blocks.
// grid = NSLAB; block b owns slab b. Single-buffered LDS (22.3 KB) +
// launch_bounds(256,5) -> 5 blocks/CU, 20 waves/CU (R13 was 4; VGPR cap 102,
// audit ~90 used). Pipelining comes from the HW scheduler interleaving
// independent blocks at different phases.
// Per block: load 16x690 fp32 (11 float4/thread, 16 thr/row) -> logit dot
// (fp32 sreg vs bf16 aw row, L2-hot, coalesced) -> bf16 convert + ds_write
// -> barrier -> 22 chunks {ds_read_b128 A, b128 wbp frag, MFMA} -> y store.
// A/B frag: k = 8*(lane>>4)+j, A row / B col = lane&15.
// D frag: col = lane&15, row = (lane>>4)*4 + reg.
// ---------------------------------------------------------------------------
__global__ __launch_bounds__(256, 5) void score_kernel(
    const float* __restrict__ x,
    const unsigned short* __restrict__ wbp,
    const unsigned short* __restrict__ awb,
    const int* __restrict__ query,
    unsigned short* __restrict__ y,
    float* __restrict__ logit)
{
    __shared__ unsigned short xs[BM * LDS_LD + 8];

    const int t = threadIdx.x;
    const int lane = t & 63;
    const int wv = t >> 6;
    const int r = lane & 15, kg = lane >> 4;
    const int srow = t >> 4, sub = t & 15;   // stage: 16 threads per row
    const int slab = blockIdx.x;

    // zero per-row pads (cols 690..695) and the 8-short tile tail:
    // kk=21 fragment tails must read finite values (paired B is exact 0).
    if (t < 52) {
        unsigned int off;  // u32 index within buffer
        if (t < 48) { int row = t / 3, c = t % 3; off = (unsigned)(row * LDS_LD + 690) / 2 + c; }
        else        { off = (unsigned)(BM * LDS_LD) / 2 + (t - 48); }
        reinterpret_cast<unsigned int*>(xs)[off] = 0u;
    }

    float4 sreg[11];

    // ---- stage loads (issue-early) ----
    {
        const float* xrow = x + ((size_t)slab * BM + srow) * DIM;
        #pragma unroll
        for (int i = 0; i < 10; ++i)
            sreg[i] = *reinterpret_cast<const float4*>(xrow + i * 64 + sub * 4);
        if (sub < 12)
            sreg[10] = *reinterpret_cast<const float4*>(xrow + 640 + sub * 4);
        else if (sub == 12) {
            float2 v = *reinterpret_cast<const float2*>(xrow + 688);
            sreg[10] = make_float4(v.x, v.y, 0.f, 0.f);
        }
    }

    // ---- logit dot: fp32 sreg vs bf16 aw row (row-shared -> coalesced) ----
    {
        const int q = query[slab * BM + srow];
        const unsigned short* awrow = awb + (size_t)q * AWLD;
        float lg = 0.f;
        #pragma unroll
        for (int i = 0; i < 10; ++i) {
            uint2 v = *reinterpret_cast<const uint2*>(awrow + i * 64 + sub * 4);
            lg += sreg[i].x * bflo(v.x) + sreg[i].y * bfhi(v.x)
                + sreg[i].z * bflo(v.y) + sreg[i].w * bfhi(v.y);
        }
        if (sub < 12) {
            uint2 v = *reinterpret_cast<const uint2*>(awrow + 640 + sub * 4);
            lg += sreg[10].x * bflo(v.x) + sreg[10].y * bfhi(v.x)
                + sreg[10].z * bflo(v.y) + sreg[10].w * bfhi(v.y);
        } else if (sub == 12) {
            unsigned int v = *reinterpret_cast<const unsigned int*>(awrow + 688);
            lg += sreg[10].x * bflo(v) + sreg[10].y * bfhi(v);
        }
        lg += __shfl_xor(lg, 1);
        lg += __shfl_xor(lg, 2);
        lg += __shfl_xor(lg, 4);
        lg += __shfl_xor(lg, 8);
        if (sub == 0) logit[slab * BM + srow] = lg;
    }

    // ---- bf16 convert + LDS write ----
    {
        unsigned short* base = xs + srow * LDS_LD;
        #pragma unroll
        for (int i = 0; i < 10; ++i) {
            uint2 p = make_uint2(f2bf(sreg[i].x) | (f2bf(sreg[i].y) << 16),
                                 f2bf(sreg[i].z) | (f2bf(sreg[i].w) << 16));
            *reinterpret_cast<uint2*>(base + i * 64 + sub * 4) = p;
        }
        if (sub < 12) {
            uint2 p = make_uint2(f2bf(sreg[10].x) | (f2bf(sreg[10].y) << 16),
                                 f2bf(sreg[10].z) | (f2bf(sreg[10].w) << 16));
            *reinterpret_cast<uint2*>(base + 640 + sub * 4) = p;
        } else if (sub == 12) {
            *reinterpret_cast<unsigned int*>(base + 688) =
                f2bf(sreg[10].x) | (f2bf(sreg[10].y) << 16);
        }
    }
    __syncthreads();

    // ---- compute: 22 chunks, pure GEMM from LDS ----
    {
        const unsigned short* xbase = xs + r * LDS_LD;
        const unsigned short* fbase = wbp + (size_t)((kg * 64 + wv * 16 + r) * 8);
        f32x4 acc = {0.f, 0.f, 0.f, 0.f};
        #pragma unroll
        for (int kk = 0; kk < NCHUNK; ++kk) {
            bf16x8 af = *reinterpret_cast<const bf16x8*>(xbase + kk * 32 + kg * 8);
            bf16x8 bw = *reinterpret_cast<const bf16x8*>(fbase + (size_t)kk * 2048);
            acc = __builtin_amdgcn_mfma_f32_16x16x32_bf16(af, bw, acc, 0, 0, 0);
        }
        const int rowBase = slab * BM;
        #pragma unroll
        for (int reg = 0; reg < 4; ++reg)
            y[(size_t)(rowBase + kg * 4 + reg) * YLD + wv * 16 + r] =
                (unsigned short)f2bf(acc[reg]);
    }
}

// ---------------------------------------------------------------------------
// K2: one block (4 waves) per bag. Wave lanes: cq=lane&15 -> cols 4cq..4cq+3
// (uint2 = 4 bf16), rq=lane>>4 -> row offset. Per instruction: 4 rows x
// 128 B contiguous. Col-indexed LDS reduce across waves.
// ---------------------------------------------------------------------------
__global__ __launch_bounds__(256) void bag_kernel(
    const unsigned short* __restrict__ y,
    const float* __restrict__ logit,
    const float* __restrict__ bias,
    const int* __restrict__ scope,
    float* __restrict__ out)
{
    const int bag = blockIdx.x;
    const int t = threadIdx.x, lane = t & 63, wv = t >> 6;
    const int s = scope[bag], e = scope[bag + 1];

    __shared__ float red[4][64];

    float m = -FLT_MAX;
    for (int i = s + lane; i < e; i += 64) m = fmaxf(m, logit[i]);
    #pragma unroll
    for (int off = 32; off > 0; off >>= 1) m = fmaxf(m, __shfl_xor(m, off));

    float sum = 0.f;
    for (int i = s + lane; i < e; i += 64) sum += __expf(logit[i] - m);
    #pragma unroll
    for (int off = 32; off > 0; off >>= 1) sum += __shfl_xor(sum, off);
    const float inv = 1.f / sum;

    const int cq = lane & 15;          // col quad: cols 4cq..4cq+3
    const int rq = lane >> 4;          // row offset 0..3
    const uint2* yu = reinterpret_cast<const uint2*>(y);

    float a0 = 0.f, a1 = 0.f, a2 = 0.f, a3 = 0.f;
    for (int base = s + wv * 4; base < e; base += 16) {
        int row = base + rq;
        if (row < e) {
            float w = __expf(logit[row] - m) * inv;
            uint2 v = yu[(size_t)row * (YLD / 4) + cq];
            a0 += w * bflo(v.x);
            a1 += w * bfhi(v.x);
            a2 += w * bflo(v.y);
            a3 += w * bfhi(v.y);
        }
    }
    a0 += __shfl_xor(a0, 16); a0 += __shfl_xor(a0, 32);
    a1 += __shfl_xor(a1, 16); a1 += __shfl_xor(a1, 32);
    a2 += __shfl_xor(a2, 16); a2 += __shfl_xor(a2, 32);
    a3 += __shfl_xor(a3, 16); a3 += __shfl_xor(a3, 32);
    if (lane < 16) {
        red[wv][4 * lane + 0] = a0;
        red[wv][4 * lane + 1] = a1;
        red[wv][4 * lane + 2] = a2;
        red[wv][4 * lane + 3] = a3;
    }
    __syncthreads();
    if (t < N_CLS)
        out[(size_t)bag * N_CLS + t] =
            red[0][t] + red[1][t] + red[2][t] + red[3][t] + bias[t];
}

// ---------------------------------------------------------------------------
extern "C" void kernel_launch(void* const* d_in, const int* in_sizes, int n_in,
                              void* d_out, int out_size, void* d_ws, size_t ws_size,
                              hipStream_t stream)
{
    const float* x     = (const float*)d_in[0];
    const float* rel_w = (const float*)d_in[1];
    const float* att_w = (const float*)d_in[2];
    const float* bias  = (const float*)d_in[3];
    const int*   query = (const int*)d_in[4];
    const int*   scope = (const int*)d_in[5];
    float*       out   = (float*)d_out;

    const int n_sent = in_sizes[0] / DIM;      // 262144
    const int n_bags = in_sizes[5] - 1;        // 8192

    // workspace layout
    const int NW = NCHUNK * 4 * 512;                           // 45056 shorts
    const int NA = N_CLS * AWLD;                               // 37312 shorts
    unsigned short* wbp   = (unsigned short*)d_ws;             // NW
    unsigned short* awb   = wbp + NW;                          // NA
    float*          logit = (float*)(awb + NA);                // n_sent
    unsigned short* y     = (unsigned short*)(logit + n_sent); // n_sent*YLD

    prep_kernel<<<(NW + NA + 255) / 256, 256, 0, stream>>>(rel_w, att_w, wbp, awb);

    score_kernel<<<NSLAB, 256, 0, stream>>>(x, wbp, awb, query, y, logit);

    bag_kernel<<<n_bags, 256, 0, stream>>>(y, logit, bias, scope, out);
}